// Round 4
// baseline (2578.544 us; speedup 1.0000x reference)
//
#include <hip/hip_runtime.h>
#include <hip/hip_bf16.h>
#include <stdint.h>

typedef unsigned short u16;
typedef __bf16 bf16x8 __attribute__((ext_vector_type(8)));
typedef float f32x4 __attribute__((ext_vector_type(4)));

#define M_DIM 8192
#define N_DIM 16384
#define K_DIM 4096

#define BM 128
#define BN 128
#define BK 64

struct alignas(8) us4 { u16 x, y, z, w; };

__device__ __forceinline__ void gload_lds16(const u16* g, u16* l) {
  __builtin_amdgcn_global_load_lds((const __attribute__((address_space(1))) void*)g,
                                   (__attribute__((address_space(3))) void*)l,
                                   16, 0, 0);
}

__device__ __forceinline__ u16 f32_to_bf16_rne_bits(float f) {
  uint32_t b = __float_as_uint(f);
  uint32_t r = b + 0x7FFFu + ((b >> 16) & 1u);
  return (u16)(r >> 16);
}

// ---------------- Pass 1: sum |W| (double accumulation) ----------------
__global__ __launch_bounds__(256) void absum_kernel(const float* __restrict__ W,
                                                    double* __restrict__ out, int n4) {
  int tid = blockIdx.x * blockDim.x + threadIdx.x;
  int stride = gridDim.x * blockDim.x;
  const float4* W4 = (const float4*)W;
  double s = 0.0;
  for (int i = tid; i < n4; i += stride) {
    float4 v = W4[i];
    s += (double)fabsf(v.x) + (double)fabsf(v.y) +
         (double)fabsf(v.z) + (double)fabsf(v.w);
  }
  for (int off = 32; off > 0; off >>= 1)
    s += __shfl_down(s, off, 64);
  __shared__ double wsum[4];
  int l = threadIdx.x & 63, w = threadIdx.x >> 6;
  if (l == 0) wsum[w] = s;
  __syncthreads();
  if (threadIdx.x == 0) {
    double t = wsum[0] + wsum[1] + wsum[2] + wsum[3];
    atomicAdd(out, t);
  }
}

// ---------------- Pass 2: ternary-quantize W -> bf16 [N][K] ----------------
__global__ __launch_bounds__(256) void quant_kernel(const float* __restrict__ W,
                                                    const double* __restrict__ gsum,
                                                    u16* __restrict__ Bq, int n4) {
  float gamma = (float)(*gsum * (1.0 / (double)((size_t)N_DIM * K_DIM))) + 1e-6f;
  int tid = blockIdx.x * blockDim.x + threadIdx.x;
  int stride = gridDim.x * blockDim.x;
  const float4* W4 = (const float4*)W;
  us4* B4 = (us4*)Bq;
  for (int i = tid; i < n4; i += stride) {
    float4 v = W4[i];
    float q0 = copysignf(fminf(rintf(fabsf(v.x / gamma)), 1.0f), v.x);
    float q1 = copysignf(fminf(rintf(fabsf(v.y / gamma)), 1.0f), v.y);
    float q2 = copysignf(fminf(rintf(fabsf(v.z / gamma)), 1.0f), v.z);
    float q3 = copysignf(fminf(rintf(fabsf(v.w / gamma)), 1.0f), v.w);
    us4 o;
    o.x = (u16)(__float_as_uint(q0) >> 16);  // {0,±1} are exact in bf16
    o.y = (u16)(__float_as_uint(q1) >> 16);
    o.z = (u16)(__float_as_uint(q2) >> 16);
    o.w = (u16)(__float_as_uint(q3) >> 16);
    B4[i] = o;
  }
}

// ---------------- Pass 3: split x into bf16 hi/lo planes ----------------
__global__ __launch_bounds__(256) void split_kernel(const float* __restrict__ x,
                                                    u16* __restrict__ hi,
                                                    u16* __restrict__ lo, int n4) {
  int tid = blockIdx.x * blockDim.x + threadIdx.x;
  int stride = gridDim.x * blockDim.x;
  const float4* X4 = (const float4*)x;
  us4* H4 = (us4*)hi;
  us4* L4 = (us4*)lo;
  for (int i = tid; i < n4; i += stride) {
    float4 v = X4[i];
    us4 h, l;
    h.x = f32_to_bf16_rne_bits(v.x);
    h.y = f32_to_bf16_rne_bits(v.y);
    h.z = f32_to_bf16_rne_bits(v.z);
    h.w = f32_to_bf16_rne_bits(v.w);
    l.x = f32_to_bf16_rne_bits(v.x - __uint_as_float((uint32_t)h.x << 16));
    l.y = f32_to_bf16_rne_bits(v.y - __uint_as_float((uint32_t)h.y << 16));
    l.z = f32_to_bf16_rne_bits(v.z - __uint_as_float((uint32_t)h.z << 16));
    l.w = f32_to_bf16_rne_bits(v.w - __uint_as_float((uint32_t)h.w << 16));
    H4[i] = h;
    L4[i] = l;
  }
}

// ---------------- Pass 4: GEMM  C[M][N] = (hi+lo)[M][K] . Bq[N][K]^T ----------------
__global__ __launch_bounds__(256, 3) void gemm_kernel(const u16* __restrict__ Ahi,
                                                      const u16* __restrict__ Alo,
                                                      const u16* __restrict__ Bq,
                                                      float* __restrict__ C) {
  __shared__ __align__(16) u16 lAhi[BM * BK];
  __shared__ __align__(16) u16 lAlo[BM * BK];
  __shared__ __align__(16) u16 lB[BN * BK];

  int wg = blockIdx.x;
  wg = (wg & 7) * 1024 + (wg >> 3);   // XCD swizzle, nwg = 8192 (multiple of 8 -> bijective)
  const int tm = wg >> 7;             // 64 row tiles
  const int tn = wg & 127;            // 128 col tiles

  const int tid = threadIdx.x;
  const int w = tid >> 6;
  const int l = tid & 63;
  const int wr = w >> 1, wc = w & 1;
  const int lr = l & 15;              // fragment row within 16
  const int lk = (l >> 4) * 8;        // k offset within 32

  // staging addressing: 16B chunk idx = i*256 + tid; row = idx>>3, col8 = (idx&7)*8
  const int rbase = tid >> 3;
  const int cbase = (tid & 7) * 8;
  const u16* pAhi = Ahi + (size_t)(tm * BM + rbase) * K_DIM + cbase;
  const u16* pAlo = Alo + (size_t)(tm * BM + rbase) * K_DIM + cbase;
  const u16* pB   = Bq  + (size_t)(tn * BN + rbase) * K_DIM + cbase;

  f32x4 acc[4][4];
#pragma unroll
  for (int i = 0; i < 4; ++i)
#pragma unroll
    for (int j = 0; j < 4; ++j)
      acc[i][j] = (f32x4){0.f, 0.f, 0.f, 0.f};

  for (int k0 = 0; k0 < K_DIM; k0 += BK) {
#pragma unroll
    for (int i = 0; i < 4; ++i) {
      // LDS dest is wave-uniform base (+ implicit lane*16); global src is per-lane
      gload_lds16(pAhi + (size_t)(i * 32) * K_DIM + k0, &lAhi[i * 2048 + w * 512]);
      gload_lds16(pAlo + (size_t)(i * 32) * K_DIM + k0, &lAlo[i * 2048 + w * 512]);
      gload_lds16(pB   + (size_t)(i * 32) * K_DIM + k0, &lB  [i * 2048 + w * 512]);
    }
    __syncthreads();   // compiler drains vmcnt before s_barrier

#pragma unroll
    for (int kk = 0; kk < 2; ++kk) {
      // b fragments once per kk, shared by both A planes (plane-outer: lower live VGPRs)
      bf16x8 b[4];
#pragma unroll
      for (int n = 0; n < 4; ++n)
        b[n] = *(const bf16x8*)&lB[(wc * 64 + n * 16 + lr) * BK + kk * 32 + lk];

      bf16x8 a[4];
#pragma unroll
      for (int m = 0; m < 4; ++m)
        a[m] = *(const bf16x8*)&lAhi[(wr * 64 + m * 16 + lr) * BK + kk * 32 + lk];
#pragma unroll
      for (int n = 0; n < 4; ++n)
#pragma unroll
        for (int m = 0; m < 4; ++m)
          acc[m][n] = __builtin_amdgcn_mfma_f32_16x16x32_bf16(a[m], b[n], acc[m][n], 0, 0, 0);

#pragma unroll
      for (int m = 0; m < 4; ++m)
        a[m] = *(const bf16x8*)&lAlo[(wr * 64 + m * 16 + lr) * BK + kk * 32 + lk];
#pragma unroll
      for (int n = 0; n < 4; ++n)
#pragma unroll
        for (int m = 0; m < 4; ++m)
          acc[m][n] = __builtin_amdgcn_mfma_f32_16x16x32_bf16(a[m], b[n], acc[m][n], 0, 0, 0);
    }
    __syncthreads();
  }

  // epilogue: D col = lane&15, row = (lane>>4)*4 + j   [m89-verified mapping]
#pragma unroll
  for (int m = 0; m < 4; ++m) {
    int row = tm * BM + wr * 64 + m * 16 + (l >> 4) * 4;
#pragma unroll
    for (int n = 0; n < 4; ++n) {
      int col = tn * BN + wc * 64 + n * 16 + lr;
      float* cp = C + (size_t)row * N_DIM + col;
#pragma unroll
      for (int j = 0; j < 4; ++j)
        cp[(size_t)j * N_DIM] = acc[m][n][j];
    }
  }
}

extern "C" void kernel_launch(void* const* d_in, const int* in_sizes, int n_in,
                              void* d_out, int out_size, void* d_ws, size_t ws_size,
                              hipStream_t stream) {
  const float* x = (const float*)d_in[0];   // [4,2048,4096] fp32 -> [8192][4096]
  const float* W = (const float*)d_in[1];   // [16384,4096] fp32
  float* C = (float*)d_out;                 // [8192][16384] fp32

  double* gsum = (double*)d_ws;
  u16* Ahi = (u16*)((char*)d_ws + 256);
  u16* Alo = Ahi + (size_t)M_DIM * K_DIM;
  u16* Bq  = Alo + (size_t)M_DIM * K_DIM;
  // ws usage: 256 B + 64 MB + 64 MB + 128 MB ≈ 256 MB

  hipMemsetAsync(d_ws, 0, 8, stream);
  absum_kernel<<<dim3(2048), dim3(256), 0, stream>>>(W, gsum, (N_DIM * K_DIM) / 4);
  quant_kernel<<<dim3(2048), dim3(256), 0, stream>>>(W, gsum, Bq, (N_DIM * K_DIM) / 4);
  split_kernel<<<dim3(2048), dim3(256), 0, stream>>>(x, Ahi, Alo, (M_DIM * K_DIM) / 4);
  gemm_kernel<<<dim3((M_DIM / BM) * (N_DIM / BN)), dim3(256), 0, stream>>>(Ahi, Alo, Bq, C);
}

// Round 5
// 2299.861 us; speedup vs baseline: 1.1212x; 1.1212x over previous
//
#include <hip/hip_runtime.h>
#include <stdint.h>

typedef int i32x4 __attribute__((ext_vector_type(4)));

#define M_DIM 8192
#define N_DIM 16384
#define K_DIM 4096

#define BM 128
#define BN 128
#define BK 64

__device__ __forceinline__ void gload_lds16(const void* g, void* l) {
  __builtin_amdgcn_global_load_lds((const __attribute__((address_space(1))) void*)g,
                                   (__attribute__((address_space(3))) void*)l,
                                   16, 0, 0);
}

// ---------------- Pass 1: sum|W| (double) + max|x| (uint-ordered float) ----------------
__global__ __launch_bounds__(256) void reduce_kernel(const float* __restrict__ W,
                                                     const float* __restrict__ x,
                                                     double* __restrict__ gsum,
                                                     unsigned* __restrict__ xmax,
                                                     int nW4, int nX4) {
  int tid = blockIdx.x * blockDim.x + threadIdx.x;
  int stride = gridDim.x * blockDim.x;
  const float4* W4 = (const float4*)W;
  const float4* X4 = (const float4*)x;
  double s = 0.0;
  for (int i = tid; i < nW4; i += stride) {
    float4 v = W4[i];
    s += (double)fabsf(v.x) + (double)fabsf(v.y) +
         (double)fabsf(v.z) + (double)fabsf(v.w);
  }
  float m = 0.f;
  for (int i = tid; i < nX4; i += stride) {
    float4 v = X4[i];
    m = fmaxf(m, fmaxf(fmaxf(fabsf(v.x), fabsf(v.y)), fmaxf(fabsf(v.z), fabsf(v.w))));
  }
  for (int off = 32; off > 0; off >>= 1) {
    s += __shfl_down(s, off, 64);
    m = fmaxf(m, __shfl_down(m, off, 64));
  }
  __shared__ double wsum[4];
  __shared__ float wmax[4];
  int l = threadIdx.x & 63, w = threadIdx.x >> 6;
  if (l == 0) { wsum[w] = s; wmax[w] = m; }
  __syncthreads();
  if (threadIdx.x == 0) {
    atomicAdd(gsum, wsum[0] + wsum[1] + wsum[2] + wsum[3]);
    float mm = fmaxf(fmaxf(wmax[0], wmax[1]), fmaxf(wmax[2], wmax[3]));
    atomicMax(xmax, __float_as_uint(mm));  // positive floats: uint order == float order
  }
}

// ---------------- Pass 2: ternary-quantize W -> i8 [N][K] ----------------
__global__ __launch_bounds__(256) void quant_kernel(const float* __restrict__ W,
                                                    const double* __restrict__ gsum,
                                                    char* __restrict__ Bq, int n4) {
  float gamma = (float)(*gsum * (1.0 / (double)((size_t)N_DIM * K_DIM))) + 1e-6f;
  int tid = blockIdx.x * blockDim.x + threadIdx.x;
  int stride = gridDim.x * blockDim.x;
  const float4* W4 = (const float4*)W;
  char4* B4 = (char4*)Bq;
  for (int i = tid; i < n4; i += stride) {
    float4 v = W4[i];
    // identical fp32 math to the verified bf16 version (same threshold behavior)
    float q0 = copysignf(fminf(rintf(fabsf(v.x / gamma)), 1.0f), v.x);
    float q1 = copysignf(fminf(rintf(fabsf(v.y / gamma)), 1.0f), v.y);
    float q2 = copysignf(fminf(rintf(fabsf(v.z / gamma)), 1.0f), v.z);
    float q3 = copysignf(fminf(rintf(fabsf(v.w / gamma)), 1.0f), v.w);
    char4 o;
    o.x = (char)(int)q0; o.y = (char)(int)q1;
    o.z = (char)(int)q2; o.w = (char)(int)q3;
    B4[i] = o;
  }
}

// ---------------- Pass 3: split x into i8 hi/lo (15-bit fixed point) ----------------
__global__ __launch_bounds__(256) void split_kernel(const float* __restrict__ x,
                                                    const unsigned* __restrict__ xmax,
                                                    char* __restrict__ hi,
                                                    char* __restrict__ lo, int n4) {
  float amax = __uint_as_float(*xmax);
  float inv = 32512.f / (amax + 1e-30f);   // |q| <= 32512 = 127*256 + 0
  int tid = blockIdx.x * blockDim.x + threadIdx.x;
  int stride = gridDim.x * blockDim.x;
  const float4* X4 = (const float4*)x;
  char4* H4 = (char4*)hi;
  char4* L4 = (char4*)lo;
  for (int i = tid; i < n4; i += stride) {
    float4 v = X4[i];
    float q[4] = {v.x, v.y, v.z, v.w};
    char hh[4], ll[4];
#pragma unroll
    for (int j = 0; j < 4; ++j) {
      float qf = fminf(fmaxf(rintf(q[j] * inv), -32512.f), 32512.f);
      float hf = rintf(qf * (1.f / 256.f));
      float lf = qf - 256.f * hf;
      if (lf > 127.f) { hf += 1.f; lf -= 256.f; }   // keep l in [-128,127]
      hh[j] = (char)(int)hf;
      ll[j] = (char)(int)lf;
    }
    char4 h = {hh[0], hh[1], hh[2], hh[3]};
    char4 l = {ll[0], ll[1], ll[2], ll[3]};
    H4[i] = h;
    L4[i] = l;
  }
}

// ---------------- Pass 4: GEMM  C = s*(256*Ah + Al) . Bq^T  (i8 MFMA, i32 acc) --------
// 512 threads = 8 waves, each owns 64x32 of the 128x128 tile.
// LDS in MFMA-fragment order: subtile = 16 rows x 16 k-bytes/lane-group = 1024 B
//   = exactly one global_load_lds wave-instr; reads are lane-linear (conflict-free).
__global__ __launch_bounds__(512, 4) void gemm_kernel(const char* __restrict__ Ahi,
                                                      const char* __restrict__ Alo,
                                                      const char* __restrict__ Bq,
                                                      const unsigned* __restrict__ xmax,
                                                      float* __restrict__ C) {
  __shared__ __align__(16) char lds[24576];  // Ahi[0,8K) Alo[8K,16K) B[16K,24K)

  int wg = blockIdx.x;
  wg = (wg & 7) * 1024 + (wg >> 3);   // XCD swizzle, 8192 % 8 == 0 -> bijective
  const int tm = wg >> 7;             // 64 row tiles
  const int tn = wg & 127;            // 128 col tiles

  const int tid = threadIdx.x;
  const int w = tid >> 6;             // 0..7
  const int l = tid & 63;
  const int wr = w >> 2;              // 0..1 : A rows wr*64
  const int wc = w & 3;               // 0..3 : B rows wc*32
  const int lr15 = l & 15;
  const int lk16 = (l >> 4) << 4;     // 0,16,32,48

  // staging: 24 subtile-jobs (Ahi 0-7, Alo 8-15, B 16-23), wave w does jobs 3w..3w+2.
  // per-lane global src = fragment-order permutation; LDS dest stays linear (rule #21).
  const char* srcs[3];
  const char* dsts[3];
#pragma unroll
  for (int j = 0; j < 3; ++j) {
    int job = w * 3 + j;
    const char* base = (job < 8) ? Ahi : (job < 16) ? Alo : Bq;
    int s = job & 7;
    int rowb = (job < 16) ? tm * BM : tn * BN;
    srcs[j] = base + (size_t)(rowb + s * 16 + lr15) * K_DIM + lk16;
    dsts[j] = &lds[job * 1024];
  }

  i32x4 acch[4][2], accl[4][2];
#pragma unroll
  for (int m = 0; m < 4; ++m)
#pragma unroll
    for (int n = 0; n < 2; ++n) {
      acch[m][n] = (i32x4){0, 0, 0, 0};
      accl[m][n] = (i32x4){0, 0, 0, 0};
    }

  for (int k0 = 0; k0 < K_DIM; k0 += BK) {
#pragma unroll
    for (int j = 0; j < 3; ++j)
      gload_lds16(srcs[j] + k0, (void*)(dsts[j]));
    __syncthreads();   // compiler drains vmcnt before s_barrier

    i32x4 b0 = *(const i32x4*)&lds[16384 + (wc * 2 + 0) * 1024 + l * 16];
    i32x4 b1 = *(const i32x4*)&lds[16384 + (wc * 2 + 1) * 1024 + l * 16];
#pragma unroll
    for (int m = 0; m < 4; ++m) {
      i32x4 a = *(const i32x4*)&lds[(wr * 4 + m) * 1024 + l * 16];
      acch[m][0] = __builtin_amdgcn_mfma_i32_16x16x64_i8(a, b0, acch[m][0], 0, 0, 0);
      acch[m][1] = __builtin_amdgcn_mfma_i32_16x16x64_i8(a, b1, acch[m][1], 0, 0, 0);
    }
#pragma unroll
    for (int m = 0; m < 4; ++m) {
      i32x4 a = *(const i32x4*)&lds[8192 + (wr * 4 + m) * 1024 + l * 16];
      accl[m][0] = __builtin_amdgcn_mfma_i32_16x16x64_i8(a, b0, accl[m][0], 0, 0, 0);
      accl[m][1] = __builtin_amdgcn_mfma_i32_16x16x64_i8(a, b1, accl[m][1], 0, 0, 0);
    }
    __syncthreads();
  }

  const float sc = __uint_as_float(*xmax) * (1.f / 32512.f);
  // D mapping (shape-determined, dtype-independent): col = lane&15, row = (lane>>4)*4 + j
#pragma unroll
  for (int m = 0; m < 4; ++m) {
    int row = tm * BM + wr * 64 + m * 16 + (l >> 4) * 4;
#pragma unroll
    for (int n = 0; n < 2; ++n) {
      int col = tn * BN + wc * 32 + n * 16 + lr15;
      float* cp = C + (size_t)row * N_DIM + col;
#pragma unroll
      for (int j = 0; j < 4; ++j)
        cp[(size_t)j * N_DIM] = sc * fmaf(256.f, (float)acch[m][n][j], (float)accl[m][n][j]);
    }
  }
}

extern "C" void kernel_launch(void* const* d_in, const int* in_sizes, int n_in,
                              void* d_out, int out_size, void* d_ws, size_t ws_size,
                              hipStream_t stream) {
  const float* x = (const float*)d_in[0];   // [4,2048,4096] fp32 -> [8192][4096]
  const float* W = (const float*)d_in[1];   // [16384,4096] fp32
  float* C = (float*)d_out;                 // [8192][16384] fp32

  double* gsum = (double*)d_ws;
  unsigned* xmax = (unsigned*)((char*)d_ws + 8);
  char* Ahi = (char*)d_ws + 256;
  char* Alo = Ahi + (size_t)M_DIM * K_DIM;          // 32 MB each
  char* Bq  = Alo + (size_t)M_DIM * K_DIM;          // 64 MB
  // ws: 256 B + 32 + 32 + 64 MB = 128 MB

  // zero BOTH scalars: ws is re-poisoned to 0xAA (0xAAAAAAAA would win atomicMax!)
  hipMemsetAsync(d_ws, 0, 16, stream);
  reduce_kernel<<<dim3(2048), dim3(256), 0, stream>>>(W, x, gsum, xmax,
                                                      (N_DIM * K_DIM) / 4,
                                                      (M_DIM * K_DIM) / 4);
  quant_kernel<<<dim3(2048), dim3(256), 0, stream>>>(W, gsum, Bq, (N_DIM * K_DIM) / 4);
  split_kernel<<<dim3(2048), dim3(256), 0, stream>>>(x, xmax, Ahi, Alo, (M_DIM * K_DIM) / 4);
  gemm_kernel<<<dim3((M_DIM / BM) * (N_DIM / BN)), dim3(512), 0, stream>>>(Ahi, Alo, Bq, xmax, C);
}